// Round 4
// baseline (1052.802 us; speedup 1.0000x reference)
//
#include <hip/hip_runtime.h>
#include <hip/hip_bf16.h>
#include <stdint.h>

typedef __bf16 bf16_t;
typedef __bf16 bf16x8 __attribute__((ext_vector_type(8)));
typedef float f32x4 __attribute__((ext_vector_type(4)));
typedef float floatv4 __attribute__((ext_vector_type(4)));

static __device__ __forceinline__ float bflo(unsigned int p){ return __uint_as_float(p << 16); }
static __device__ __forceinline__ float bfhi(unsigned int p){ return __uint_as_float(p & 0xffff0000u); }
static __device__ __forceinline__ unsigned int pack2(float lo, float hi){
  union { bf16_t h[2]; unsigned int u; } o;
  o.h[0] = (bf16_t)lo; o.h[1] = (bf16_t)hi;
  return o.u;
}

constexpr int NN = 100000;
constexpr int NE = 1600000;
// Sliced bf16 feature layout: addr(node, f) = base + ((f>>4)*NN + node)*32B + (f&15)*2
// slice = 16 features = 32B; one buffer = 8 slices x 3.2MB (fits one XCD L2 per slice).

// ---------------- CSR build ----------------
__global__ void k_count(const int* __restrict__ row, int* __restrict__ cnt,
                        int* __restrict__ pos, int e){
  int i = blockIdx.x*256 + threadIdx.x;
  if (i < e) pos[i] = atomicAdd(&cnt[row[i]], 1);
}

__global__ void k_scan1(const int* __restrict__ cnt, int* __restrict__ tmp,
                        int* __restrict__ bsum, int n){
  __shared__ int s[256];
  int i = blockIdx.x*256 + threadIdx.x;
  s[threadIdx.x] = (i < n) ? cnt[i] : 0;
  __syncthreads();
  for (int off = 1; off < 256; off <<= 1){
    int t = (threadIdx.x >= off) ? s[threadIdx.x - off] : 0;
    __syncthreads();
    s[threadIdx.x] += t;
    __syncthreads();
  }
  if (i < n) tmp[i] = s[threadIdx.x];
  if (threadIdx.x == 255) bsum[blockIdx.x] = s[255];
}

__global__ void k_scan2(int* bsum, int nb){
  if (threadIdx.x == 0 && blockIdx.x == 0){
    int run = 0;
    for (int b = 0; b < nb; ++b){ int t = bsum[b]; bsum[b] = run; run += t; }
  }
}

__global__ void k_scan3(const int* __restrict__ tmp, const int* __restrict__ bsum,
                        int* __restrict__ rowptr, int n){
  int i = blockIdx.x*256 + threadIdx.x;
  if (i < n) rowptr[i+1] = tmp[i] + bsum[blockIdx.x];
  if (i == 0) rowptr[0] = 0;
}

__global__ void k_fill2(const int* __restrict__ row, const int* __restrict__ col,
                        const float* __restrict__ w, const int* __restrict__ rowptr,
                        const int* __restrict__ pos, int2* __restrict__ ecw, int e){
  int i = blockIdx.x*256 + threadIdx.x;
  if (i < e){
    int r = row[i];
    int p = rowptr[r] + pos[i];
    ecw[p] = make_int2(col[i], __float_as_int(w[i]));
  }
}

__global__ __launch_bounds__(256) void k_deg2(const int2* __restrict__ ecw,
                                              const int* __restrict__ rowptr,
                                              float* __restrict__ dinv, int n){
  int node = blockIdx.x*4 + (threadIdx.x >> 6);
  if (node >= n) return;
  int lane = threadIdx.x & 63;
  int e0 = rowptr[node], e1 = rowptr[node+1];
  float s = 0.f;
  for (int e = e0 + lane; e < e1; e += 64) s += __int_as_float(ecw[e].y);
  #pragma unroll
  for (int off = 32; off > 0; off >>= 1) s += __shfl_xor(s, off, 64);
  if (lane == 0) dinv[node] = (s > 0.f) ? rsqrtf(s) : 0.f;
}

__global__ __launch_bounds__(256) void k_norm(int2* __restrict__ ecw,
                                              const int* __restrict__ rowptr,
                                              const float* __restrict__ dinv, int n){
  int node = blockIdx.x*4 + (threadIdx.x >> 6);
  if (node >= n) return;
  int lane = threadIdx.x & 63;
  int e0 = rowptr[node], e1 = rowptr[node+1];
  float dr = -dinv[node];
  for (int e = e0 + lane; e < e1; e += 64){
    int2 p = ecw[e];
    float wn = dr * __int_as_float(p.y) * dinv[p.x];
    ecw[e] = make_int2(p.x, __float_as_int(wn));
  }
}

__global__ void k_transw_all(const float* __restrict__ W1, const float* __restrict__ c1W,
                             const float* __restrict__ c2W, bf16_t* __restrict__ Wt1,
                             bf16_t* __restrict__ Wtc1, bf16_t* __restrict__ Wtc2){
  int idx = blockIdx.x*256 + threadIdx.x;   // 8*16384 total
  const float* src; bf16_t* dst; int local;
  if (idx < 2*16384)      { src = W1;  dst = Wt1;  local = idx; }
  else if (idx < 5*16384) { src = c1W; dst = Wtc1; local = idx - 2*16384; }
  else                    { src = c2W; dst = Wtc2; local = idx - 5*16384; }
  int c = local >> 14, r = (local >> 7) & 127, j = local & 127;
  dst[(c << 14) + (j << 7) + r] = (bf16_t)src[local];
}

// ---------------- GEMM: OUT_sliced(Mx128) = relu?( [A0|A1|A2] @ Wt^T + bias ) ------
// SRCF32: A = row-major f32 (the x input). else: A = sliced bf16 buffers.
// Output always sliced bf16.
template<bool SRCF32, int NCHUNK>
__global__ __launch_bounds__(256) void k_gemm(
    const void* __restrict__ a0, const void* __restrict__ a1, const void* __restrict__ a2,
    int astride,
    const bf16_t* __restrict__ Wt, const float* __restrict__ bias,
    bf16_t* __restrict__ out, int M, int dorelu)
{
  __shared__ bf16_t As[128][40];
  const int tid = threadIdx.x;
  const int wave = tid >> 6, lane = tid & 63;
  const int wm = wave >> 1, wn = wave & 1;
  const int l15 = lane & 15, lq = lane >> 4;
  const int blockRow = blockIdx.x * 128;

  f32x4 acc[4][4];
  #pragma unroll
  for (int a = 0; a < 4; ++a)
    #pragma unroll
    for (int b = 0; b < 4; ++b) acc[a][b] = f32x4{0.f,0.f,0.f,0.f};

  const int srow = tid >> 1;
  const int scol = (tid & 1) * 16;
  const int grow = blockRow + srow;

  #pragma unroll
  for (int chunk = 0; chunk < NCHUNK; ++chunk){
    const void* src = (chunk == 0) ? a0 : ((chunk == 1) ? a1 : a2);
    #pragma unroll
    for (int k4 = 0; k4 < 4; ++k4){
      const int kk = k4 * 32;
      {
        union { bf16_t h[16]; uint4 q[2]; } u;
        if (grow < M){
          if (SRCF32){
            const float* p = (const float*)src + (size_t)grow*astride + kk + scol;
            floatv4 vv[4];
            #pragma unroll
            for (int j = 0; j < 4; ++j) vv[j] = *(const floatv4*)(p + j*4);
            #pragma unroll
            for (int j = 0; j < 16; ++j) u.h[j] = (bf16_t)vv[j>>2][j&3];
          } else {
            // sliced: features [kk+scol, +16) = slice (kk+scol)>>4, full 32B cell
            const char* p = (const char*)src + ((size_t)(((kk + scol) >> 4) * NN + grow)) * 32;
            u.q[0] = *(const uint4*)p;
            u.q[1] = *(const uint4*)(p + 16);
          }
        } else {
          u.q[0] = make_uint4(0,0,0,0);
          u.q[1] = make_uint4(0,0,0,0);
        }
        *(uint4*)&As[srow][scol]     = u.q[0];
        *(uint4*)&As[srow][scol + 8] = u.q[1];
      }
      __syncthreads();
      bf16x8 af[4], bfr[4];
      #pragma unroll
      for (int fm = 0; fm < 4; ++fm)
        af[fm] = *(const bf16x8*)&As[wm*64 + fm*16 + l15][lq*8];
      #pragma unroll
      for (int fn = 0; fn < 4; ++fn){
        int colg = wn*64 + fn*16 + l15;
        bfr[fn] = *(const bf16x8*)&Wt[((size_t)((chunk << 7) + colg) << 7) + kk + lq*8];
      }
      #pragma unroll
      for (int fm = 0; fm < 4; ++fm)
        #pragma unroll
        for (int fn = 0; fn < 4; ++fn)
          acc[fm][fn] = __builtin_amdgcn_mfma_f32_16x16x32_bf16(af[fm], bfr[fn], acc[fm][fn], 0, 0, 0);
      __syncthreads();
    }
  }
  // epilogue: bias + relu + sliced bf16 store (slice = wn*4+fn, offset = l15)
  #pragma unroll
  for (int fm = 0; fm < 4; ++fm){
    #pragma unroll
    for (int j = 0; j < 4; ++j){
      int r = wm*64 + fm*16 + lq*4 + j;
      int growo = blockRow + r;
      if (growo < M){
        #pragma unroll
        for (int fn = 0; fn < 4; ++fn){
          float v = acc[fm][fn][j] + bias[wn*64 + fn*16 + l15];
          if (dorelu) v = fmaxf(v, 0.f);
          char* po = (char*)out + ((size_t)((wn*4 + fn)*NN + growo))*32 + l15*2;
          *(bf16_t*)po = (bf16_t)v;
        }
      }
    }
  }
}

// ---------------- SpMM sliced: out[i] = alpha*sum_e wn[e]*V[col[e]] (- sub[i]) ------
// grid = 8 slices x 3125 node-chunks; slice = bid%8 -> pinned to one XCD by
// round-robin dispatch => V slice (3.2MB) stays resident in that XCD's 4MB L2.
// 8 lanes per node (4B = 2 feats each), 32 nodes per block.
__global__ __launch_bounds__(256) void k_spmm_s(
    const int* __restrict__ rowptr, const int2* __restrict__ ecw,
    const bf16_t* __restrict__ V, const bf16_t* __restrict__ sub, float alpha,
    bf16_t* __restrict__ out, int n)
{
  const int slice = blockIdx.x & 7;
  const int chunk = blockIdx.x >> 3;
  const int tid = threadIdx.x;
  const int node = chunk*32 + (tid >> 6)*8 + ((tid >> 3) & 7);
  const int sw = tid & 7;                       // dword within the 32B slice cell
  if (node >= n) return;

  const char* Vb = (const char*)V + (size_t)slice*NN*32 + sw*4;
  int e = rowptr[node];
  const int e1 = rowptr[node+1];
  float a0 = 0.f, a1 = 0.f;

  for (; e + 4 <= e1; e += 4){
    long long q0 = __builtin_nontemporal_load((const long long*)(ecw + e));
    long long q1 = __builtin_nontemporal_load((const long long*)(ecw + e + 1));
    long long q2 = __builtin_nontemporal_load((const long long*)(ecw + e + 2));
    long long q3 = __builtin_nontemporal_load((const long long*)(ecw + e + 3));
    unsigned p0 = *(const unsigned*)(Vb + ((size_t)(unsigned)(int)q0) * 32);
    unsigned p1 = *(const unsigned*)(Vb + ((size_t)(unsigned)(int)q1) * 32);
    unsigned p2 = *(const unsigned*)(Vb + ((size_t)(unsigned)(int)q2) * 32);
    unsigned p3 = *(const unsigned*)(Vb + ((size_t)(unsigned)(int)q3) * 32);
    float w0 = __int_as_float((int)(q0 >> 32)), w1 = __int_as_float((int)(q1 >> 32));
    float w2 = __int_as_float((int)(q2 >> 32)), w3 = __int_as_float((int)(q3 >> 32));
    a0 += w0*bflo(p0); a1 += w0*bfhi(p0);
    a0 += w1*bflo(p1); a1 += w1*bfhi(p1);
    a0 += w2*bflo(p2); a1 += w2*bfhi(p2);
    a0 += w3*bflo(p3); a1 += w3*bfhi(p3);
  }
  for (; e < e1; ++e){
    long long q = __builtin_nontemporal_load((const long long*)(ecw + e));
    unsigned p = *(const unsigned*)(Vb + ((size_t)(unsigned)(int)q) * 32);
    float w = __int_as_float((int)(q >> 32));
    a0 += w*bflo(p); a1 += w*bfhi(p);
  }

  float r0 = alpha*a0, r1 = alpha*a1;
  if (sub){
    unsigned sv = *(const unsigned*)((const char*)sub + ((size_t)(slice*NN + node))*32 + sw*4);
    r0 -= bflo(sv); r1 -= bfhi(sv);
  }
  unsigned* ob = (unsigned*)((char*)out + ((size_t)(slice*NN + node))*32 + sw*4);
  __builtin_nontemporal_store(pack2(r0, r1), ob);
}

// ---------------- head: logits = h@W2 + b2 ; softmax over 2 classes ----------------
__global__ __launch_bounds__(256) void k_head(
    const bf16_t* __restrict__ h, const float* __restrict__ W2, const float* __restrict__ b2,
    float* __restrict__ out, int n)
{
  int node = blockIdx.x*4 + (threadIdx.x >> 6);
  if (node >= n) return;
  int lane = threadIdx.x & 63;
  // features f = 2*lane, 2*lane+1 -> slice = lane>>3, dword = lane&7
  const char* hb = (const char*)h + ((size_t)((lane >> 3)*NN + node))*32 + (lane & 7)*4;
  unsigned p = *(const unsigned*)hb;
  float h0 = bflo(p), h1 = bfhi(p);
  floatv4 w = *(const floatv4*)(W2 + lane*4);
  float p0 = h0*w[0] + h1*w[2];
  float p1 = h0*w[1] + h1*w[3];
  #pragma unroll
  for (int s = 32; s > 0; s >>= 1){
    p0 += __shfl_xor(p0, s, 64);
    p1 += __shfl_xor(p1, s, 64);
  }
  if (lane == 0){
    float l0 = p0 + b2[0], l1 = p1 + b2[1];
    float m = fmaxf(l0, l1);
    float e0 = __expf(l0 - m), e1 = __expf(l1 - m);
    float inv = 1.f / (e0 + e1);
    out[(size_t)node*2]     = e0 * inv;
    out[(size_t)node*2 + 1] = e1 * inv;
  }
}

// ---------------- launch ----------------

extern "C" void kernel_launch(void* const* d_in, const int* in_sizes, int n_in,
                              void* d_out, int out_size, void* d_ws, size_t ws_size,
                              hipStream_t stream)
{
  const float* x   = (const float*)d_in[0];
  const int*   ei  = (const int*)d_in[1];
  const float* ew  = (const float*)d_in[2];
  const float* W1  = (const float*)d_in[3];
  const float* b1  = (const float*)d_in[4];
  const float* c1W = (const float*)d_in[5];
  const float* c1b = (const float*)d_in[6];
  const float* c2W = (const float*)d_in[7];
  const float* c2b = (const float*)d_in[8];
  const float* W2  = (const float*)d_in[9];
  const float* b2  = (const float*)d_in[10];
  float* out = (float*)d_out;

  const int n = NN, e = NE;
  const int* row = ei;
  const int* col = ei + e;

  char* ws = (char*)d_ws;
  size_t off = 0;
  auto carve = [&](size_t bytes)->void*{
    void* p = ws + off;
    off += (bytes + 255) & ~(size_t)255;
    return p;
  };
  bf16_t* A    = (bf16_t*)carve((size_t)n*128*2);
  bf16_t* B    = (bf16_t*)carve((size_t)n*128*2);
  bf16_t* C    = (bf16_t*)carve((size_t)n*128*2);
  bf16_t* D    = (bf16_t*)carve((size_t)n*128*2);
  float*  dinv = (float*)carve((size_t)n*4);
  int*    cnt  = (int*)carve((size_t)n*4);
  int*    rowptr = (int*)carve((size_t)(n+1)*4);
  int*    bsum = (int*)carve(512*4);
  int2*   ecw  = (int2*)carve((size_t)e*8);
  bf16_t* Wt1  = (bf16_t*)carve(2*128*128*2);
  bf16_t* Wtc1 = (bf16_t*)carve(3*128*128*2);
  bf16_t* Wtc2 = (bf16_t*)carve(3*128*128*2);
  // aliases (lifetimes end before their hosts are first written):
  int* pos = (int*)B;     // used k_count..k_fill2; B first written by spmm later
  int* tmp = (int*)C;     // used scan1..scan3; C first written by spmm later
  (void)ws_size; (void)in_sizes; (void)n_in; (void)out_size;

  const int NB_N = (n + 255)/256;   // 391
  const int NB_E = (e + 255)/256;   // 6250
  const int NB_G = (n + 127)/128;   // 782
  const int NB_W = (n + 3)/4;       // 25000
  const int NB_S = ((n + 31)/32)*8; // 25000 (8 slices x 3125 chunks)

  hipMemsetAsync(cnt, 0, (size_t)n*4, stream);
  k_count<<<NB_E,256,0,stream>>>(row, cnt, pos, e);
  k_scan1<<<NB_N,256,0,stream>>>(cnt, tmp, bsum, n);
  k_scan2<<<1,64,0,stream>>>(bsum, NB_N);
  k_scan3<<<NB_N,256,0,stream>>>(tmp, bsum, rowptr, n);
  k_fill2<<<NB_E,256,0,stream>>>(row, col, ew, rowptr, pos, ecw, e);
  k_deg2<<<NB_W,256,0,stream>>>(ecw, rowptr, dinv, n);
  k_norm<<<NB_W,256,0,stream>>>(ecw, rowptr, dinv, n);
  k_transw_all<<<(8*16384+255)/256,256,0,stream>>>(W1, c1W, c2W, Wt1, Wtc1, Wtc2);

  // h0 = relu(x @ W1 + b1)        -> A (sliced)
  k_gemm<true,2><<<NB_G,256,0,stream>>>(x, x+128, nullptr, 256, Wt1, b1, A, n, 1);
  // conv1: Tx1 = Lx(h0)           -> B
  k_spmm_s<<<NB_S,256,0,stream>>>(rowptr, ecw, A, nullptr, 1.f, B, n);
  //        Tx2 = 2*Lx(Tx1) - h0   -> C
  k_spmm_s<<<NB_S,256,0,stream>>>(rowptr, ecw, B, A, 2.f, C, n);
  //        h1 = relu([A|B|C] @ Wc1 + b) -> D
  k_gemm<false,3><<<NB_G,256,0,stream>>>(A, B, C, 128, Wtc1, c1b, D, n, 1);
  // conv2
  k_spmm_s<<<NB_S,256,0,stream>>>(rowptr, ecw, D, nullptr, 1.f, B, n);
  k_spmm_s<<<NB_S,256,0,stream>>>(rowptr, ecw, B, D, 2.f, C, n);
  k_gemm<false,3><<<NB_G,256,0,stream>>>(D, B, C, 128, Wtc2, c2b, A, n, 1);
  // head
  k_head<<<NB_W,256,0,stream>>>(A, W2, b2, out, n);
}

// Round 5
// 578.149 us; speedup vs baseline: 1.8210x; 1.8210x over previous
//
#include <hip/hip_runtime.h>
#include <hip/hip_bf16.h>
#include <stdint.h>

typedef __bf16 bf16_t;
typedef __bf16 bf16x8 __attribute__((ext_vector_type(8)));
typedef float f32x4 __attribute__((ext_vector_type(4)));
typedef float floatv4 __attribute__((ext_vector_type(4)));

static __device__ __forceinline__ float bflo(unsigned int p){ return __uint_as_float(p << 16); }
static __device__ __forceinline__ float bfhi(unsigned int p){ return __uint_as_float(p & 0xffff0000u); }
static __device__ __forceinline__ unsigned int pack2(float lo, float hi){
  union { bf16_t h[2]; unsigned int u; } o;
  o.h[0] = (bf16_t)lo; o.h[1] = (bf16_t)hi;
  return o.u;
}

constexpr int NN = 100000;
constexpr int NE = 1600000;
constexpr int NB_G = (NN + 127)/128;   // 782 GEMM tile blocks
constexpr int NB_E = (NE + 255)/256;   // 6250 edge chunks

// ---------------- small prep kernels ----------------

__global__ void k_scan1(const int* __restrict__ cnt, int* __restrict__ tmp,
                        int* __restrict__ bsum, int n){
  __shared__ int s[256];
  int i = blockIdx.x*256 + threadIdx.x;
  s[threadIdx.x] = (i < n) ? cnt[i] : 0;
  __syncthreads();
  for (int off = 1; off < 256; off <<= 1){
    int t = (threadIdx.x >= off) ? s[threadIdx.x - off] : 0;
    __syncthreads();
    s[threadIdx.x] += t;
    __syncthreads();
  }
  if (i < n) tmp[i] = s[threadIdx.x];
  if (threadIdx.x == 255) bsum[blockIdx.x] = s[255];
}

__global__ void k_scan2(int* bsum, int nb){
  if (threadIdx.x == 0 && blockIdx.x == 0){
    int run = 0;
    for (int b = 0; b < nb; ++b){ int t = bsum[b]; bsum[b] = run; run += t; }
  }
}

__global__ void k_scan3(const int* __restrict__ tmp, const int* __restrict__ bsum,
                        int* __restrict__ rowptr, int n){
  int i = blockIdx.x*256 + threadIdx.x;
  if (i < n) rowptr[i+1] = tmp[i] + bsum[blockIdx.x];
  if (i == 0) rowptr[0] = 0;
}

__global__ void k_fill2(const int* __restrict__ row, const int* __restrict__ col,
                        const float* __restrict__ w, const int* __restrict__ rowptr,
                        const int* __restrict__ pos, int2* __restrict__ ecw, int e){
  int i = blockIdx.x*256 + threadIdx.x;
  if (i < e){
    int r = row[i];
    int p = rowptr[r] + pos[i];
    ecw[p] = make_int2(col[i], __float_as_int(w[i]));
  }
}

__global__ __launch_bounds__(256) void k_deg2(const int2* __restrict__ ecw,
                                              const int* __restrict__ rowptr,
                                              float* __restrict__ dinv, int n){
  int node = blockIdx.x*4 + (threadIdx.x >> 6);
  if (node >= n) return;
  int lane = threadIdx.x & 63;
  int e0 = rowptr[node], e1 = rowptr[node+1];
  float s = 0.f;
  for (int e = e0 + lane; e < e1; e += 64) s += __int_as_float(ecw[e].y);
  #pragma unroll
  for (int off = 32; off > 0; off >>= 1) s += __shfl_xor(s, off, 64);
  if (lane == 0) dinv[node] = (s > 0.f) ? rsqrtf(s) : 0.f;
}

__global__ __launch_bounds__(256) void k_norm(int2* __restrict__ ecw,
                                              const int* __restrict__ rowptr,
                                              const float* __restrict__ dinv, int n){
  int node = blockIdx.x*4 + (threadIdx.x >> 6);
  if (node >= n) return;
  int lane = threadIdx.x & 63;
  int e0 = rowptr[node], e1 = rowptr[node+1];
  float dr = -dinv[node];
  for (int e = e0 + lane; e < e1; e += 64){
    int2 p = ecw[e];
    float wn = dr * __int_as_float(p.y) * dinv[p.x];
    ecw[e] = make_int2(p.x, __float_as_int(wn));
  }
}

__global__ void k_transw_all(const float* __restrict__ W1, const float* __restrict__ c1W,
                             const float* __restrict__ c2W, bf16_t* __restrict__ Wt1,
                             bf16_t* __restrict__ Wtc1, bf16_t* __restrict__ Wtc2){
  int idx = blockIdx.x*256 + threadIdx.x;   // 8*16384 total
  const float* src; bf16_t* dst; int local;
  if (idx < 2*16384)      { src = W1;  dst = Wt1;  local = idx; }
  else if (idx < 5*16384) { src = c1W; dst = Wtc1; local = idx - 2*16384; }
  else                    { src = c2W; dst = Wtc2; local = idx - 5*16384; }
  int c = local >> 14, r = (local >> 7) & 127, j = local & 127;
  dst[(c << 14) + (j << 7) + r] = (bf16_t)src[local];
}

// ---------------- fused: GEMM1 (blocks < NB_G) + edge-count (rest) ----------------
// GEMM1: A = relu(x @ W1 + b1), x f32 row-major (K=256), LDS-staged, row-major bf16 out.
// count: pos[i] = rank of edge i within its row (one returning atomic per edge).
__global__ __launch_bounds__(256) void k_gemm1_count(
    const float* __restrict__ x, const bf16_t* __restrict__ Wt, const float* __restrict__ bias,
    bf16_t* __restrict__ out, int M,
    const int* __restrict__ row, int* __restrict__ cnt, int* __restrict__ pos, int e)
{
  if (blockIdx.x >= NB_G){
    int i = (blockIdx.x - NB_G)*256 + threadIdx.x;
    if (i < e) pos[i] = atomicAdd(&cnt[row[i]], 1);
    return;
  }
  __shared__ bf16_t As[128][40];
  const int tid = threadIdx.x;
  const int wave = tid >> 6, lane = tid & 63;
  const int wm = wave >> 1, wn = wave & 1;
  const int l15 = lane & 15, lq = lane >> 4;
  const int blockRow = blockIdx.x * 128;

  f32x4 acc[4][4];
  #pragma unroll
  for (int a = 0; a < 4; ++a)
    #pragma unroll
    for (int b = 0; b < 4; ++b) acc[a][b] = f32x4{0.f,0.f,0.f,0.f};

  const int srow = tid >> 1;
  const int scol = (tid & 1) * 16;
  const int grow = blockRow + srow;

  #pragma unroll
  for (int chunk = 0; chunk < 2; ++chunk){
    #pragma unroll
    for (int k4 = 0; k4 < 4; ++k4){
      const int kk = k4 * 32;
      {
        union { bf16_t h[16]; uint4 q[2]; } u;
        if (grow < M){
          const float* p = x + (size_t)grow*256 + chunk*128 + kk + scol;
          floatv4 vv[4];
          #pragma unroll
          for (int j = 0; j < 4; ++j) vv[j] = *(const floatv4*)(p + j*4);
          #pragma unroll
          for (int j = 0; j < 16; ++j) u.h[j] = (bf16_t)vv[j>>2][j&3];
        } else {
          u.q[0] = make_uint4(0,0,0,0);
          u.q[1] = make_uint4(0,0,0,0);
        }
        *(uint4*)&As[srow][scol]     = u.q[0];
        *(uint4*)&As[srow][scol + 8] = u.q[1];
      }
      __syncthreads();
      bf16x8 af[4], bfr[4];
      #pragma unroll
      for (int fm = 0; fm < 4; ++fm)
        af[fm] = *(const bf16x8*)&As[wm*64 + fm*16 + l15][lq*8];
      #pragma unroll
      for (int fn = 0; fn < 4; ++fn){
        int colg = wn*64 + fn*16 + l15;
        bfr[fn] = *(const bf16x8*)&Wt[((size_t)((chunk << 7) + colg) << 7) + kk + lq*8];
      }
      #pragma unroll
      for (int fm = 0; fm < 4; ++fm)
        #pragma unroll
        for (int fn = 0; fn < 4; ++fn)
          acc[fm][fn] = __builtin_amdgcn_mfma_f32_16x16x32_bf16(af[fm], bfr[fn], acc[fm][fn], 0, 0, 0);
      __syncthreads();
    }
  }
  #pragma unroll
  for (int fm = 0; fm < 4; ++fm){
    #pragma unroll
    for (int j = 0; j < 4; ++j){
      int growo = blockRow + wm*64 + fm*16 + lq*4 + j;
      if (growo < M){
        #pragma unroll
        for (int fn = 0; fn < 4; ++fn){
          int c = wn*64 + fn*16 + l15;
          float v = fmaxf(acc[fm][fn][j] + bias[c], 0.f);
          out[((size_t)growo << 7) + c] = (bf16_t)v;
        }
      }
    }
  }
}

// ---------------- conv GEMM, barrier-free: OUT = relu([A0|A1|A2] @ Wt^T + b) ------
// A chunks row-major bf16 [node][128]; A frags + Wt frags loaded directly from
// global (L2/L3-hot, no cross-block A reuse at N=128 -> LDS staging not worth
// 24 barriers). Zero __syncthreads in the whole kernel.
__global__ __launch_bounds__(256) void k_gemm_nb(
    const bf16_t* __restrict__ a0, const bf16_t* __restrict__ a1, const bf16_t* __restrict__ a2,
    const bf16_t* __restrict__ Wt, const float* __restrict__ bias,
    bf16_t* __restrict__ out, int M)
{
  const int tid = threadIdx.x;
  const int wave = tid >> 6, lane = tid & 63;
  const int wm = wave >> 1, wn = wave & 1;
  const int l15 = lane & 15, lq = lane >> 4;
  const int blockRow = blockIdx.x * 128;
  const int arow = blockRow + wm*64 + l15;   // + fm*16
  // NOTE: last block reads A rows [100000,100096) — spills into the next ws
  // buffer (allocated, value-irrelevant); those acc rows are never stored.

  f32x4 acc[4][4];
  #pragma unroll
  for (int a = 0; a < 4; ++a)
    #pragma unroll
    for (int b = 0; b < 4; ++b) acc[a][b] = f32x4{0.f,0.f,0.f,0.f};

  #pragma unroll
  for (int chunk = 0; chunk < 3; ++chunk){
    const bf16_t* src = (chunk == 0) ? a0 : ((chunk == 1) ? a1 : a2);
    #pragma unroll
    for (int k4 = 0; k4 < 4; ++k4){
      const int kk = k4*32 + lq*8;
      bf16x8 af[4], bfr[4];
      #pragma unroll
      for (int fm = 0; fm < 4; ++fm)
        af[fm] = *(const bf16x8*)(src + (((size_t)(arow + fm*16)) << 7) + kk);
      #pragma unroll
      for (int fn = 0; fn < 4; ++fn)
        bfr[fn] = *(const bf16x8*)(Wt + ((size_t)((chunk << 7) + wn*64 + fn*16 + l15) << 7) + kk);
      #pragma unroll
      for (int fm = 0; fm < 4; ++fm)
        #pragma unroll
        for (int fn = 0; fn < 4; ++fn)
          acc[fm][fn] = __builtin_amdgcn_mfma_f32_16x16x32_bf16(af[fm], bfr[fn], acc[fm][fn], 0, 0, 0);
    }
  }
  #pragma unroll
  for (int fm = 0; fm < 4; ++fm){
    #pragma unroll
    for (int j = 0; j < 4; ++j){
      int growo = blockRow + wm*64 + fm*16 + lq*4 + j;
      if (growo < M){
        #pragma unroll
        for (int fn = 0; fn < 4; ++fn){
          int c = wn*64 + fn*16 + l15;
          float v = fmaxf(acc[fm][fn][j] + bias[c], 0.f);
          out[((size_t)growo << 7) + c] = (bf16_t)v;
        }
      }
    }
  }
}

// ---------------- SpMM (round-3 proven): 4 nodes/wave, 16 lanes/node, 16B/lane ----
static __device__ __forceinline__ void accum8(float* a, uint4 p, float w){
  a[0] += w*bflo(p.x); a[1] += w*bfhi(p.x);
  a[2] += w*bflo(p.y); a[3] += w*bfhi(p.y);
  a[4] += w*bflo(p.z); a[5] += w*bfhi(p.z);
  a[6] += w*bflo(p.w); a[7] += w*bfhi(p.w);
}

__global__ __launch_bounds__(256) void k_spmm4(
    const int* __restrict__ rowptr, const int2* __restrict__ ecw,
    const bf16_t* __restrict__ V, const bf16_t* __restrict__ sub, float alpha,
    bf16_t* __restrict__ out, int n)
{
  const int lane = threadIdx.x & 63;
  const int wave = threadIdx.x >> 6;
  const int g = lane >> 4;
  const int s = lane & 15;
  const int node = blockIdx.x*16 + wave*4 + g;
  if (node >= n) return;

  int e = rowptr[node];
  const int e1 = rowptr[node+1];
  const char* Vb = (const char*)V;
  const int fb = s << 4;

  float acc[8] = {0.f,0.f,0.f,0.f,0.f,0.f,0.f,0.f};

  for (; e + 4 <= e1; e += 4){
    int2 q0 = ecw[e], q1 = ecw[e+1], q2 = ecw[e+2], q3 = ecw[e+3];
    uint4 p0 = *(const uint4*)(Vb + (((size_t)(unsigned)q0.x) << 8) + fb);
    uint4 p1 = *(const uint4*)(Vb + (((size_t)(unsigned)q1.x) << 8) + fb);
    uint4 p2 = *(const uint4*)(Vb + (((size_t)(unsigned)q2.x) << 8) + fb);
    uint4 p3 = *(const uint4*)(Vb + (((size_t)(unsigned)q3.x) << 8) + fb);
    accum8(acc, p0, __int_as_float(q0.y));
    accum8(acc, p1, __int_as_float(q1.y));
    accum8(acc, p2, __int_as_float(q2.y));
    accum8(acc, p3, __int_as_float(q3.y));
  }
  for (; e < e1; ++e){
    int2 q = ecw[e];
    uint4 p = *(const uint4*)(Vb + (((size_t)(unsigned)q.x) << 8) + fb);
    accum8(acc, p, __int_as_float(q.y));
  }

  uint4 o;
  if (sub){
    uint4 sv = *(const uint4*)((const char*)sub + (((size_t)node) << 8) + fb);
    o.x = pack2(alpha*acc[0] - bflo(sv.x), alpha*acc[1] - bfhi(sv.x));
    o.y = pack2(alpha*acc[2] - bflo(sv.y), alpha*acc[3] - bfhi(sv.y));
    o.z = pack2(alpha*acc[4] - bflo(sv.z), alpha*acc[5] - bfhi(sv.z));
    o.w = pack2(alpha*acc[6] - bflo(sv.w), alpha*acc[7] - bfhi(sv.w));
  } else {
    o.x = pack2(alpha*acc[0], alpha*acc[1]);
    o.y = pack2(alpha*acc[2], alpha*acc[3]);
    o.z = pack2(alpha*acc[4], alpha*acc[5]);
    o.w = pack2(alpha*acc[6], alpha*acc[7]);
  }
  *(uint4*)((char*)out + (((size_t)node) << 8) + fb) = o;
}

// ---------------- head ----------------
__global__ __launch_bounds__(256) void k_head(
    const bf16_t* __restrict__ h, const float* __restrict__ W2, const float* __restrict__ b2,
    float* __restrict__ out, int n)
{
  int node = blockIdx.x*4 + (threadIdx.x >> 6);
  if (node >= n) return;
  int lane = threadIdx.x & 63;
  unsigned int p = *(const unsigned int*)(h + ((size_t)node << 7) + lane*2);
  float h0 = bflo(p), h1 = bfhi(p);
  floatv4 w = *(const floatv4*)(W2 + lane*4);
  float p0 = h0*w[0] + h1*w[2];
  float p1 = h0*w[1] + h1*w[3];
  #pragma unroll
  for (int s = 32; s > 0; s >>= 1){
    p0 += __shfl_xor(p0, s, 64);
    p1 += __shfl_xor(p1, s, 64);
  }
  if (lane == 0){
    float l0 = p0 + b2[0], l1 = p1 + b2[1];
    float m = fmaxf(l0, l1);
    float e0 = __expf(l0 - m), e1 = __expf(l1 - m);
    float inv = 1.f / (e0 + e1);
    out[(size_t)node*2]     = e0 * inv;
    out[(size_t)node*2 + 1] = e1 * inv;
  }
}

// ---------------- launch ----------------

extern "C" void kernel_launch(void* const* d_in, const int* in_sizes, int n_in,
                              void* d_out, int out_size, void* d_ws, size_t ws_size,
                              hipStream_t stream)
{
  const float* x   = (const float*)d_in[0];
  const int*   ei  = (const int*)d_in[1];
  const float* ew  = (const float*)d_in[2];
  const float* W1  = (const float*)d_in[3];
  const float* b1  = (const float*)d_in[4];
  const float* c1W = (const float*)d_in[5];
  const float* c1b = (const float*)d_in[6];
  const float* c2W = (const float*)d_in[7];
  const float* c2b = (const float*)d_in[8];
  const float* W2  = (const float*)d_in[9];
  const float* b2  = (const float*)d_in[10];
  float* out = (float*)d_out;

  const int n = NN, e = NE;
  const int* row = ei;
  const int* col = ei + e;

  char* ws = (char*)d_ws;
  size_t off = 0;
  auto carve = [&](size_t bytes)->void*{
    void* p = ws + off;
    off += (bytes + 255) & ~(size_t)255;
    return p;
  };
  bf16_t* A    = (bf16_t*)carve((size_t)n*128*2);
  bf16_t* B    = (bf16_t*)carve((size_t)n*128*2);
  bf16_t* C    = (bf16_t*)carve((size_t)n*128*2);
  bf16_t* D    = (bf16_t*)carve((size_t)n*128*2);
  float*  dinv = (float*)carve((size_t)n*4);
  int*    cnt  = (int*)carve((size_t)n*4);
  int*    rowptr = (int*)carve((size_t)(n+1)*4);
  int*    bsum = (int*)carve(512*4);
  int2*   ecw  = (int2*)carve((size_t)e*8);
  bf16_t* Wt1  = (bf16_t*)carve(2*128*128*2);
  bf16_t* Wtc1 = (bf16_t*)carve(3*128*128*2);
  bf16_t* Wtc2 = (bf16_t*)carve(3*128*128*2);
  // aliases (lifetimes end before their hosts are first written):
  int* pos = (int*)B;     // used fused..k_fill2; B first written by spmm later
  int* tmp = (int*)C;     // used scan1..scan3; C first written by spmm later
  (void)ws_size; (void)in_sizes; (void)n_in; (void)out_size;

  const int NB_N = (n + 255)/256;   // 391
  const int NB_W = (n + 3)/4;       // 25000
  const int NB_S = (n + 15)/16;     // 6250

  hipMemsetAsync(cnt, 0, (size_t)n*4, stream);
  k_transw_all<<<(8*16384+255)/256,256,0,stream>>>(W1, c1W, c2W, Wt1, Wtc1, Wtc2);
  // fused: h0 = relu(x @ W1 + b1) -> A   AND   per-edge count/rank
  k_gemm1_count<<<NB_G + NB_E,256,0,stream>>>(x, Wt1, b1, A, n, row, cnt, pos, e);
  k_scan1<<<NB_N,256,0,stream>>>(cnt, tmp, bsum, n);
  k_scan2<<<1,64,0,stream>>>(bsum, NB_N);
  k_scan3<<<NB_N,256,0,stream>>>(tmp, bsum, rowptr, n);
  k_fill2<<<NB_E,256,0,stream>>>(row, col, ew, rowptr, pos, ecw, e);
  k_deg2<<<NB_W,256,0,stream>>>(ecw, rowptr, dinv, n);
  k_norm<<<NB_W,256,0,stream>>>(ecw, rowptr, dinv, n);

  // conv1: Tx1 = Lx(h0) -> B ; Tx2 = 2*Lx(Tx1) - h0 -> C
  k_spmm4<<<NB_S,256,0,stream>>>(rowptr, ecw, A, nullptr, 1.f, B, n);
  k_spmm4<<<NB_S,256,0,stream>>>(rowptr, ecw, B, A, 2.f, C, n);
  k_gemm_nb<<<NB_G,256,0,stream>>>(A, B, C, Wtc1, c1b, D, n);
  // conv2
  k_spmm4<<<NB_S,256,0,stream>>>(rowptr, ecw, D, nullptr, 1.f, B, n);
  k_spmm4<<<NB_S,256,0,stream>>>(rowptr, ecw, B, D, 2.f, C, n);
  k_gemm_nb<<<NB_G,256,0,stream>>>(D, B, C, Wtc2, c2b, A, n);
  // head
  k_head<<<NB_W,256,0,stream>>>(A, W2, b2, out, n);
}